// Round 2
// baseline (328.193 us; speedup 1.0000x reference)
//
#include <hip/hip_runtime.h>

// Block-sparse causal flash attention, MI355X gfx950.
// B=2 T=2048 H=16 D=128; BLOCK_M=BLOCK_N=64; mask[B,H,32,32] int32.
// HARNESS DTYPE CONTRACT: reference is fp16, but harness only supports
// bf16/f32/int — fp16 inputs arrive as float32, output buffer is float32.
// We convert f32 -> f16 at staging (lossless: data born fp16) and run the
// MFMA pipeline in fp16.
// 1 workgroup (4 waves) per (b,h,qblock); wave owns 16 q-rows x 128 Dv.
// mfma_f32_16x16x32_f16; K in LDS [64][136] (+8 pad), V transposed [128][72],
// P per-wave LDS round-trip (C-layout -> A-layout, per m120 verified pattern).

typedef _Float16 half8 __attribute__((ext_vector_type(8)));
typedef float floatx4 __attribute__((ext_vector_type(4)));

#define B_ 2
#define T_ 2048
#define H_ 16
#define D_ 128
#define BM 64
#define BN 64
#define NQ (T_ / BM)
#define NK (T_ / BN)

__device__ inline half8 cvt8(const float4 a, const float4 b) {
    half8 r;
    r[0] = (_Float16)a.x; r[1] = (_Float16)a.y;
    r[2] = (_Float16)a.z; r[3] = (_Float16)a.w;
    r[4] = (_Float16)b.x; r[5] = (_Float16)b.y;
    r[6] = (_Float16)b.z; r[7] = (_Float16)b.w;
    return r;
}

__global__ __launch_bounds__(256, 2)
void bsattn_kernel(const float* __restrict__ qg,
                   const float* __restrict__ kg,
                   const float* __restrict__ vg,
                   const int* __restrict__ maskg,
                   float* __restrict__ outg)
{
    const int blk = blockIdx.x;
    const int qi = blk % NQ;
    const int h  = (blk / NQ) % H_;
    const int b  = blk / (NQ * H_);

    const int tid  = threadIdx.x;
    const int wave = tid >> 6;
    const int lane = tid & 63;
    const int l16  = lane & 15;
    const int quad = lane >> 4;

    __shared__ _Float16 Ksh[64][136];      // K tile, row-padded (+8 halves)
    __shared__ _Float16 Vsh[128][72];      // V tile transposed: Vsh[d][s]
    __shared__ _Float16 Psh[4][16][72];    // per-wave P round-trip buffer

    // Q A-frags: lane holds Q[m=l16][k = kc*32 + quad*8 + j], j=0..7
    half8 qf[4];
    {
        const int qrow = qi * BM + wave * 16 + l16;
        const float* qp = qg + (((size_t)b * T_ + qrow) * H_ + h) * D_;
        #pragma unroll
        for (int kc = 0; kc < 4; ++kc) {
            float4 a = *(const float4*)(qp + kc * 32 + quad * 8);
            float4 c = *(const float4*)(qp + kc * 32 + quad * 8 + 4);
            qf[kc] = cvt8(a, c);
        }
    }

    floatx4 acc[8];
    #pragma unroll
    for (int t = 0; t < 8; ++t) acc[t] = (floatx4)0.0f;
    float m_i[4], l_i[4];
    #pragma unroll
    for (int r = 0; r < 4; ++r) { m_i[r] = -INFINITY; l_i[r] = 0.0f; }

    // softmax in base-2 scaled domain: s2 = s * (1/sqrt(D)) * log2(e)
    const float c_scale = 0.08838834764831845f * 1.44269504088896341f;

    const int* mrow = maskg + (((size_t)b * H_ + h) * NQ + qi) * NK;
    const size_t kvbase = ((size_t)b * T_) * (H_ * D_) + (size_t)h * D_;

    for (int j = 0; j <= qi; ++j) {
        if (mrow[j] == 0) continue;            // block-uniform skip
        const bool diag = (j == qi);

        __syncthreads();                       // protect prev iter's LDS reads
        // Stage K [64][128] and V (transposed) into LDS. 1024 chunks of 8 elems.
        #pragma unroll
        for (int c = tid; c < 1024; c += 256) {
            const int s  = c >> 4;             // kv row in tile
            const int d8 = (c & 15) << 3;      // d start
            const size_t goff = kvbase + (size_t)(j * BN + s) * (H_ * D_) + d8;
            float4 k0 = *(const float4*)(kg + goff);
            float4 k1 = *(const float4*)(kg + goff + 4);
            *(half8*)(&Ksh[s][d8]) = cvt8(k0, k1);
            float4 v0 = *(const float4*)(vg + goff);
            float4 v1 = *(const float4*)(vg + goff + 4);
            half8 vh = cvt8(v0, v1);
            #pragma unroll
            for (int e = 0; e < 8; ++e) Vsh[d8 + e][s] = vh[e];
        }
        __syncthreads();

        // S = Q K^T : 4 kv col-tiles, K-dim 128 = 4 chunks of 32
        floatx4 sc[4];
        #pragma unroll
        for (int t = 0; t < 4; ++t) {
            floatx4 cacc = (floatx4)0.0f;
            #pragma unroll
            for (int kc = 0; kc < 4; ++kc) {
                half8 bf = *(const half8*)(&Ksh[t * 16 + l16][kc * 32 + quad * 8]);
                cacc = __builtin_amdgcn_mfma_f32_16x16x32_f16(qf[kc], bf, cacc, 0, 0, 0);
            }
            sc[t] = cacc;
        }

        // scale (+causal mask on diagonal block), online softmax update
        float alpha[4];
        #pragma unroll
        for (int r = 0; r < 4; ++r) {
            const int qrl = wave * 16 + quad * 4 + r;   // q row local to 64-block
            float mv = -INFINITY;
            #pragma unroll
            for (int t = 0; t < 4; ++t) {
                float s = sc[t][r] * c_scale;
                if (diag && (t * 16 + l16) > qrl) s = -INFINITY;
                sc[t][r] = s;
                mv = fmaxf(mv, s);
            }
            mv = fmaxf(mv, __shfl_xor(mv, 1));
            mv = fmaxf(mv, __shfl_xor(mv, 2));
            mv = fmaxf(mv, __shfl_xor(mv, 4));
            mv = fmaxf(mv, __shfl_xor(mv, 8));
            const float mnew = fmaxf(m_i[r], mv);
            alpha[r] = __builtin_amdgcn_exp2f(m_i[r] - mnew);
            m_i[r] = mnew;
            float rs = 0.0f;
            #pragma unroll
            for (int t = 0; t < 4; ++t) {
                float p = __builtin_amdgcn_exp2f(sc[t][r] - mnew);
                sc[t][r] = p;
                rs += p;
            }
            rs += __shfl_xor(rs, 1);
            rs += __shfl_xor(rs, 2);
            rs += __shfl_xor(rs, 4);
            rs += __shfl_xor(rs, 8);
            l_i[r] = l_i[r] * alpha[r] + rs;
        }

        // P: C-layout regs -> LDS (fp16) -> A-layout frags (wave-private)
        #pragma unroll
        for (int t = 0; t < 4; ++t)
            #pragma unroll
            for (int r = 0; r < 4; ++r)
                Psh[wave][quad * 4 + r][t * 16 + l16] = (_Float16)sc[t][r];

        // rescale running O by alpha
        #pragma unroll
        for (int t8 = 0; t8 < 8; ++t8)
            #pragma unroll
            for (int r = 0; r < 4; ++r)
                acc[t8][r] *= alpha[r];

        half8 pf[2];
        #pragma unroll
        for (int kc = 0; kc < 2; ++kc)
            pf[kc] = *(const half8*)(&Psh[wave][l16][kc * 32 + quad * 8]);

        // O += P V : 8 Dv col-tiles, K-dim 64 = 2 chunks of 32
        #pragma unroll
        for (int t8 = 0; t8 < 8; ++t8) {
            #pragma unroll
            for (int kc = 0; kc < 2; ++kc) {
                half8 vf = *(const half8*)(&Vsh[t8 * 16 + l16][kc * 32 + quad * 8]);
                acc[t8] = __builtin_amdgcn_mfma_f32_16x16x32_f16(pf[kc], vf, acc[t8], 0, 0, 0);
            }
        }
    }

    // epilogue: O / l, store float32 (harness reads d_out as f32)
    #pragma unroll
    for (int r = 0; r < 4; ++r) {
        const float inv = 1.0f / l_i[r];
        const int qrow = qi * BM + wave * 16 + quad * 4 + r;
        float* op = outg + (((size_t)b * T_ + qrow) * H_ + h) * D_;
        #pragma unroll
        for (int t8 = 0; t8 < 8; ++t8)
            op[t8 * 16 + l16] = acc[t8][r] * inv;
    }
}

extern "C" void kernel_launch(void* const* d_in, const int* in_sizes, int n_in,
                              void* d_out, int out_size, void* d_ws, size_t ws_size,
                              hipStream_t stream) {
    const float* q  = (const float*)d_in[0];
    const float* k  = (const float*)d_in[1];
    const float* v  = (const float*)d_in[2];
    const int* mask = (const int*)d_in[3];
    float* out      = (float*)d_out;

    dim3 grid(B_ * H_ * NQ);   // 1024 workgroups
    bsattn_kernel<<<grid, 256, 0, stream>>>(q, k, v, mask, out);
}